// Round 8
// baseline (226.980 us; speedup 1.0000x reference)
//
#include <hip/hip_runtime.h>
#include <hip/hip_fp16.h>

typedef _Float16 half8 __attribute__((ext_vector_type(8)));
typedef _Float16 half4 __attribute__((ext_vector_type(4)));
typedef float f32x4 __attribute__((ext_vector_type(4)));
typedef float f32x16 __attribute__((ext_vector_type(16)));
typedef int  i32x8 __attribute__((ext_vector_type(8)));

#define B_   4
#define L_   4096
#define D_   128
#define M_   (B_*L_)     // 16384
#define D2_  256
#define H_   512
#define OUT_ 55

__device__ __forceinline__ f32x4 mfma16(half8 a, half8 b, f32x4 c) {
    return __builtin_amdgcn_mfma_f32_16x16x32_f16(a, b, c, 0, 0, 0);
}
// MX-scaled fp8 MFMA, 32x32x64, unit scales (E8M0 127 = 1.0). fmt 0 = OCP e4m3.
__device__ __forceinline__ f32x16 mfma_mx32(i32x8 a, i32x8 b, f32x16 c) {
    return __builtin_amdgcn_mfma_scale_f32_32x32x64_f8f6f4(a, b, c, 0, 0, 0, 127, 0, 127);
}
// pack 4 floats -> 4 fp8 e4m3 bytes (OCP on gfx950)
__device__ __forceinline__ int pk4(float a, float b, float c, float d) {
    int t = __builtin_amdgcn_cvt_pk_fp8_f32(a, b, 0, false);
    return __builtin_amdgcn_cvt_pk_fp8_f32(c, d, t, true);
}
__device__ __forceinline__ float fexp2(float x) { return __builtin_amdgcn_exp2f(x); }

// fold softmax scale (1/sqrt(128)) * log2(e) into k2 so score uses bare v_exp
#define KSCL (0.08838834764831845f * 1.4426950408889634f)

// ---- weight swizzle offsets (in halfs) within wsw region ----
#define WQ_OFF   0
#define WV1_OFF  16384
#define WK_OFF   32768
#define WV2_OFF  49152
#define WP1_OFF  65536
#define WP2_OFF  81920
#define WF1_OFF  98304     // 256x512 = 131072
#define WF2_OFF  229376    // 512x256 = 131072
#define WO_OFF   360448    // 256x64 (padded) = 16384

// ---- shared 64-k-chunk fragment map for the MX 32x32x64 path ----
// hw position (g = lane>>5, byte j=0..31) -> logical k = 16*i + 4*(2g+jh) + r
// with j = 16*jh + 4*i + r.  P (score) and V (proj) both write this map;
// pv consumes both, so any hw-internal k-order cancels (A/B mirror).
// Memory: P per batch  [att32(128)][k64(64)][lane64][32B] = 16 MB
//         V per batch  [k64(64)][vcol32(8)][lane64][32B]  =  1 MB
// lane64 = (row-within-32-tile) + 32*g.

__global__ void prep_kernel(const float* Wq, const float* Wv1, const float* Wk,
                            const float* Wv2, const float* Wp1, const float* Wp2,
                            const float* Wf1, const float* Wf2, const float* Wo,
                            _Float16* wsw, float* rowsum) {
    int id = blockIdx.y;
    int t  = blockIdx.x * 256 + threadIdx.x;
    if (id == 9) {
        if (t < 4096) ((f32x4*)rowsum)[t] = f32x4{0.f, 0.f, 0.f, 0.f};
        return;
    }
    const float* src = nullptr; int K = 0, N = 0, Npad = 0, off = 0;
    switch (id) {
        case 0: src = Wq;  K = 128; N = 128; Npad = 128; off = WQ_OFF;  break;
        case 1: src = Wv1; K = 128; N = 128; Npad = 128; off = WV1_OFF; break;
        case 2: src = Wk;  K = 128; N = 128; Npad = 128; off = WK_OFF;  break;
        case 3: src = Wv2; K = 128; N = 128; Npad = 128; off = WV2_OFF; break;
        case 4: src = Wp1; K = 128; N = 128; Npad = 128; off = WP1_OFF; break;
        case 5: src = Wp2; K = 128; N = 128; Npad = 128; off = WP2_OFF; break;
        case 6: src = Wf1; K = 256; N = 512; Npad = 512; off = WF1_OFF; break;
        case 7: src = Wf2; K = 512; N = 256; Npad = 256; off = WF2_OFF; break;
        case 8: src = Wo;  K = 256; N = 55;  Npad = 64;  off = WO_OFF;  break;
        default: return;
    }
    int total = K * Npad;
    if (t >= total) return;
    int k = t / Npad, n = t % Npad;
    float v = (n < N) ? src[k * N + n] : 0.f;
    int s = k >> 5, c = n >> 4, ln = n & 15;
    int q, j;
    if (id == 4 || id == 5) { q = (k >> 2) & 3; j = (k & 3) + (((k >> 4) & 1) << 2); }
    else                    { q = (k >> 3) & 3; j = k & 7; }
    int nc = Npad >> 4;
    wsw[off + ((size_t)((s * nc + c) * 64 + q * 16 + ln)) * 8 + j] = (_Float16)v;
}

// FR layout for X[M][C] halfs:
// idx = ((lt*(C/32) + s)*64 + q*16 + ln_r)*8 + j ; lt=row>>4, ln_r=row&15,
// s=col>>5, q=(col>>3)&3, j=col&7.

__global__ __launch_bounds__(256) void proj_kernel(const float* x1, const float* x2,
        const _Float16* wsw,
        const float* ln1_g, const float* ln1_b, const float* ln2_g, const float* ln2_b,
        const float* bq, const float* bv1, const float* bk, const float* bv2,
        _Float16* q1, _Float16* k2, unsigned char* vsw8) {
    int g2 = blockIdx.y;  // 0: stream 1, 1: stream 2
    const float* X  = g2 ? x2 : x1;
    const float* lg = g2 ? ln2_g : ln1_g;
    const float* lb = g2 ? ln2_b : ln1_b;
    int wave = threadIdx.x >> 6, lane = threadIdx.x & 63;
    int quad = lane >> 4, ln = lane & 15;
    int mbase = blockIdx.x * 64 + wave * 16;
    int lt = mbase >> 4;

    // ---- fused LN: this lane holds row (mbase+ln), cols s*32+quad*8..+7 ----
    const float* xr = X + (size_t)(mbase + ln) * D_;
    float xv[4][8];
    float sum = 0.f, sq = 0.f;
    #pragma unroll
    for (int s = 0; s < 4; s++) {
        f32x4 v0 = *(const f32x4*)(xr + s * 32 + quad * 8);
        f32x4 v1 = *(const f32x4*)(xr + s * 32 + quad * 8 + 4);
        #pragma unroll
        for (int j = 0; j < 4; j++) {
            xv[s][j]     = v0[j];
            xv[s][j + 4] = v1[j];
            sum += v0[j] + v1[j];
            sq  += v0[j] * v0[j] + v1[j] * v1[j];
        }
    }
    sum += __shfl_xor(sum, 16); sum += __shfl_xor(sum, 32);
    sq  += __shfl_xor(sq, 16);  sq  += __shfl_xor(sq, 32);
    float mean = sum * (1.f / 128.f);
    float var  = sq * (1.f / 128.f) - mean * mean;
    float inv  = rsqrtf(var + 1e-5f);
    half8 a[4];
    #pragma unroll
    for (int s = 0; s < 4; s++) {
        f32x4 g0 = *(const f32x4*)(lg + s * 32 + quad * 8);
        f32x4 g1 = *(const f32x4*)(lg + s * 32 + quad * 8 + 4);
        f32x4 b0 = *(const f32x4*)(lb + s * 32 + quad * 8);
        f32x4 b1 = *(const f32x4*)(lb + s * 32 + quad * 8 + 4);
        #pragma unroll
        for (int j = 0; j < 4; j++) {
            a[s][j]     = (_Float16)((xv[s][j] - mean) * inv * g0[j] + b0[j]);
            a[s][j + 4] = (_Float16)((xv[s][j + 4] - mean) * inv * g1[j] + b1[j]);
        }
    }

    // ---- pipeline 0: Q/K projection -> fp16 FR ----
    {
        const _Float16* Bw = wsw + (g2 ? WK_OFF : WQ_OFF);
        const float* bias = g2 ? bk : bq;
        float scl = g2 ? KSCL : 1.f;
        _Float16* out = g2 ? k2 : q1;
        f32x4 acc[8];
        #pragma unroll
        for (int c = 0; c < 8; c++) acc[c] = f32x4{0.f, 0.f, 0.f, 0.f};
        half8 Wc[4], Wn[4];
        #pragma unroll
        for (int s = 0; s < 4; s++)
            Wc[s] = *(const half8*)(Bw + ((size_t)((s * 8 + 0) * 64 + lane)) * 8);
        #pragma unroll
        for (int c = 0; c < 8; c++) {
            int cn = (c < 7) ? c + 1 : 7;
            #pragma unroll
            for (int s = 0; s < 4; s++)
                Wn[s] = *(const half8*)(Bw + ((size_t)((s * 8 + cn) * 64 + lane)) * 8);
            #pragma unroll
            for (int s = 0; s < 4; s++)
                acc[c] = mfma16(a[s], Wc[s], acc[c]);
            #pragma unroll
            for (int s = 0; s < 4; s++) Wc[s] = Wn[s];
        }
        #pragma unroll
        for (int c = 0; c < 8; c++) {
            int n = c * 16 + ln;
            float bv = bias[n];
            #pragma unroll
            for (int r = 0; r < 4; r++) {
                int s_o = c >> 1, q_o = ((c & 1) << 1) | (ln >> 3), j = ln & 7;
                out[((size_t)((lt * 4 + s_o) * 64 + q_o * 16 + (quad * 4 + r))) * 8 + j]
                    = (_Float16)((acc[c][r] + bv) * scl);
            }
        }
    }

    // ---- pipeline 1: V projection -> fp8, MX 32x32x64 A-fragment layout ----
    {
        const _Float16* Bw = wsw + (g2 ? WV2_OFF : WV1_OFF);
        const float* bias = g2 ? bv2 : bv1;
        int cbase = g2 ? 8 : 0;
        f32x4 acc[8];
        #pragma unroll
        for (int c = 0; c < 8; c++) acc[c] = f32x4{0.f, 0.f, 0.f, 0.f};
        half8 Wc[4], Wn[4];
        #pragma unroll
        for (int s = 0; s < 4; s++)
            Wc[s] = *(const half8*)(Bw + ((size_t)((s * 8 + 0) * 64 + lane)) * 8);
        #pragma unroll
        for (int c = 0; c < 8; c++) {
            int cn = (c < 7) ? c + 1 : 7;
            #pragma unroll
            for (int s = 0; s < 4; s++)
                Wn[s] = *(const half8*)(Bw + ((size_t)((s * 8 + cn) * 64 + lane)) * 8);
            #pragma unroll
            for (int s = 0; s < 4; s++)
                acc[c] = mfma16(a[s], Wc[s], acc[c]);
            #pragma unroll
            for (int s = 0; s < 4; s++) Wc[s] = Wn[s];
        }
        // k position of acc[c][r] within its 64-k chunk: 16*wave + 4*quad + r
        // -> i = wave, g = quad>>1, jh = quad&1, byte = 16*jh + 4*i + r.
        int b = mbase >> 12;
        int k64 = (mbase & (L_ - 1)) >> 6;       // = blockIdx.x & 63
        int gg = quad >> 1, jh = quad & 1;
        unsigned char* Vb = vsw8 + (size_t)b * (1u << 20);
        #pragma unroll
        for (int c = 0; c < 8; c++) {
            int n = c * 16 + ln;
            float bv = bias[n];
            int pk = pk4(acc[c][0] + bv, acc[c][1] + bv, acc[c][2] + bv, acc[c][3] + bv);
            int v32 = (cbase + c) >> 1;                       // vcol 32-tile (0..7)
            int lane32 = ((c & 1) << 4) + ln + 32 * gg;       // row-in-tile + 32g
            *(int*)(Vb + ((size_t)((k64 * 8 + v32) * 64 + lane32)) * 32 + 16 * jh + 4 * wave) = pk;
        }
    }
}

// Pass 1: S^T tiles (A=q1 rows = softmax k-dim, B=k2^T cols = att rows).
// 16x16 MFMA kept; P store addresses target the MX 32x32x64 B-fragment layout.
// XCD-aware block swizzle: each XCD works a contiguous q1-row band.
__global__ __launch_bounds__(256) void score_kernel(
        const _Float16* __restrict__ q1sw, const _Float16* __restrict__ k2sw,
        unsigned char* __restrict__ pmat8, float* __restrict__ rowsum) {
    int w = threadIdx.x >> 6, lane = threadIdx.x & 63;
    int quad = lane >> 4, ln = lane & 15;
    int b = blockIdx.z;
    int id0 = blockIdx.y * 32 + blockIdx.x;        // 0..1023 within batch
    int id  = ((id0 & 7) << 7) + (id0 >> 3);       // bijective XCD chunking
    int bx = id & 31, by = id >> 5;
    int kL0 = by * 128 + (w & 1) * 64;             // q1 rows (contraction dim of PV)
    int mL0 = bx * 128 + (w >> 1) * 64;            // k2 rows (att rows)
    int ltk = ((b << 12) + kL0) >> 4;
    int ltm = ((b << 12) + mL0) >> 4;

    f32x4 acc[4][4];
    #pragma unroll
    for (int i = 0; i < 4; i++)
        #pragma unroll
        for (int j = 0; j < 4; j++) acc[i][j] = f32x4{0.f, 0.f, 0.f, 0.f};

    #pragma unroll
    for (int s = 0; s < 4; s++) {
        half8 a[4], bq[4];
        #pragma unroll
        for (int i = 0; i < 4; i++)
            a[i] = *(const half8*)(q1sw + ((size_t)(((ltk + i) * 4 + s) * 64 + lane)) * 8);
        #pragma unroll
        for (int j = 0; j < 4; j++)
            bq[j] = *(const half8*)(k2sw + ((size_t)(((ltm + j) * 4 + s) * 64 + lane)) * 8);
        #pragma unroll
        for (int i = 0; i < 4; i++)
            #pragma unroll
            for (int j = 0; j < 4; j++)
                acc[i][j] = mfma16(a[i], bq[j], acc[i][j]);
    }

    unsigned char* Pb = pmat8 + (size_t)b * (16u << 20);
    int k64 = kL0 >> 6;
    int gg = quad >> 1, jh = quad & 1;
    #pragma unroll
    for (int j = 0; j < 4; j++) {
        int4 d;
        float csum = 0.f;
        #pragma unroll
        for (int i = 0; i < 4; i++) {
            float p0 = fexp2(acc[i][j][0]);
            float p1 = fexp2(acc[i][j][1]);
            float p2 = fexp2(acc[i][j][2]);
            float p3 = fexp2(acc[i][j][3]);
            csum += (p0 + p1) + (p2 + p3);
            ((int*)&d)[i] = pk4(p0, p1, p2, p3);   // byte 4i+r -> k 16i+4*quad+r
        }
        csum += __shfl_xor(csum, 16);
        csum += __shfl_xor(csum, 32);
        if (lane < 16)
            atomicAdd(&rowsum[(b << 12) + mL0 + j * 16 + ln], csum);
        int att32 = (mL0 >> 5) + (j >> 1);
        int a32 = ((j & 1) << 4) + ln;             // att row within 32-tile
        *(int4*)(Pb + ((size_t)((att32 * 64 + k64) * 64 + a32 + 32 * gg)) * 32 + 16 * jh) = d;
    }
}

// Pass 2 FUSED: pv + attn_out.
// Phase A: O^T = V^T.P^T, MX fp8 32x32x64, 8 waves (wc, kh), k-half partials
// merged in 32 KB LDS. r8: P ring depth 6 (HBM/L3 stream, issue->use ~6
// half-steps), V triple-buffer (L2 stream, ~3 half-steps). r7's depth-4 P
// helped (48->46.4us) but waves still park on waitcnt (MfmaUtil 14%); VGPR
// was 80, so spend the headroom on in-flight depth (~112, keeps 4 waves/SIMD).
// Phase B: normalized fp16 O-tile -> 16 KB LDS attT (FR, block-local rows).
// Phase C: out_s = att_s @ Wp_s + bias + residual; LNf -> res, xn.
__global__ __launch_bounds__(512) void pv_kernel(
        const unsigned char* __restrict__ pmat8, const unsigned char* __restrict__ vsw8,
        const float* __restrict__ rowsum, const _Float16* __restrict__ wsw,
        const float* bp1, const float* bp2,
        const float* x1, const float* x2, const float* lnf_g, const float* lnf_b,
        _Float16* __restrict__ res, _Float16* __restrict__ xn) {
    __shared__ f32x4 part[4][2][4][64];   // 32 KB: [wc][t][q][lane]; reused in C
    __shared__ _Float16 attT[2][4096];    // 16 KB: per stream, 32 rows x 128 cols FR
    __shared__ float sstA[2][16][2][2];   // 1 KB: LNf cross-stream stats
    int w = threadIdx.x >> 6, lane = threadIdx.x & 63;
    int quad = lane >> 4, ln = lane & 15;
    int wc = w & 3, kh = w >> 2;
    int id0 = blockIdx.x;                          // 0..511
    int bid = ((id0 & 7) << 6) + (id0 >> 3);       // bijective XCD chunking
    int rowG0 = bid * 32;
    int b = rowG0 >> 12;
    int att32 = (rowG0 & (L_ - 1)) >> 5;
    const unsigned char* Pb = pmat8 + (size_t)b * (16u << 20);
    const unsigned char* Vb = vsw8 + (size_t)b * (1u << 20);

    const unsigned char* Vbase = Vb + (size_t)(wc * 2) * 2048 + (size_t)lane * 32;
    const unsigned char* Pbase = Pb + (size_t)att32 * 131072 + (size_t)lane * 32;
    int sp0 = kh * 32;

    f32x16 acc0, acc1;
    #pragma unroll
    for (int i = 0; i < 16; i++) { acc0[i] = 0.f; acc1[i] = 0.f; }

    #define VLOAD2(dA, dB, sp) do {                                           \
        dA = *(const i32x8*)(Vbase + (size_t)(sp) * 16384);                   \
        dB = *(const i32x8*)(Vbase + (size_t)(sp) * 16384 + 2048);            \
    } while (0)
    #define PLOAD(dP, sp) do {                                                \
        dP = *(const i32x8*)(Pbase + (size_t)(sp) * 2048);                    \
    } while (0)
    #define CLMP(x) (((x) < 32) ? (x) : 31)

    i32x8 a0, b0, a1, b1, a2, b2, na, nb;
    i32x8 p0, p1, p2, p3, p4, p5, np;
    VLOAD2(a0, b0, sp0);
    VLOAD2(a1, b1, sp0 + 1);
    VLOAD2(a2, b2, sp0 + 2);
    PLOAD(p0, sp0);
    PLOAD(p1, sp0 + 1);
    PLOAD(p2, sp0 + 2);
    PLOAD(p3, sp0 + 3);
    PLOAD(p4, sp0 + 4);
    PLOAD(p5, sp0 + 5);
    for (int ii = 0; ii < 32; ii += 2) {
        VLOAD2(na, nb, sp0 + CLMP(ii + 3));
        PLOAD(np, sp0 + CLMP(ii + 6));
        __builtin_amdgcn_s_setprio(1);
        acc0 = mfma_mx32(a0, p0, acc0);
        acc1 = mfma_mx32(b0, p0, acc1);
        __builtin_amdgcn_s_setprio(0);
        a0 = a1; b0 = b1; a1 = a2; b1 = b2; a2 = na; b2 = nb;
        p0 = p1; p1 = p2; p2 = p3; p3 = p4; p4 = p5; p5 = np;
        VLOAD2(na, nb, sp0 + CLMP(ii + 4));
        PLOAD(np, sp0 + CLMP(ii + 7));
        __builtin_amdgcn_s_setprio(1);
        acc0 = mfma_mx32(a0, p0, acc0);
        acc1 = mfma_mx32(b0, p0, acc1);
        __builtin_amdgcn_s_setprio(0);
        a0 = a1; b0 = b1; a1 = a2; b1 = b2; a2 = na; b2 = nb;
        p0 = p1; p1 = p2; p2 = p3; p3 = p4; p4 = p5; p5 = np;
    }
    #undef VLOAD2
    #undef PLOAD
    #undef CLMP

    if (kh == 1) {
        #pragma unroll
        for (int q = 0; q < 4; q++) {
            part[wc][0][q][lane] = f32x4{acc0[q * 4 + 0], acc0[q * 4 + 1],
                                         acc0[q * 4 + 2], acc0[q * 4 + 3]};
            part[wc][1][q][lane] = f32x4{acc1[q * 4 + 0], acc1[q * 4 + 1],
                                         acc1[q * 4 + 2], acc1[q * 4 + 3]};
        }
    }
    __syncthreads();
    if (kh == 0) {
        // D: col = att row = lane&31 ; row = Vcol-in-tile = (reg&3)+8*(reg>>2)+4*g
        int rowL = lane & 31;
        float inv = 1.f / rowsum[rowG0 + rowL];
        int g = lane >> 5;
        int ltl = rowL >> 4, lnr = lane & 15;
        #pragma unroll
        for (int t = 0; t < 2; t++) {
            int v32 = wc * 2 + t;
            int stw = (v32 >= 4);
            int s = v32 & 3;
            #pragma unroll
            for (int q = 0; q < 4; q++) {
                f32x4 pp = part[wc][t][q][lane];
                half4 hv;
                #pragma unroll
                for (int rr = 0; rr < 4; rr++) {
                    float v = ((t == 0) ? acc0[q * 4 + rr] : acc1[q * 4 + rr]) + pp[rr];
                    hv[rr] = (_Float16)(v * inv);
                }
                // FR (block-local rows): j = 4g + rr
                *(half4*)(&attT[stw][((ltl * 4 + s) * 64 + q * 16 + lnr) * 8 + 4 * g]) = hv;
            }
        }
    }
    __syncthreads();

    // ---- phase C: att @ Wp + bias + residual ; LNf -> res, xn ----
    {
        int rt = w & 1, st = (w >> 1) & 1, kh2 = w >> 2;
        const _Float16* Wp = wsw + (st ? WP2_OFF : WP1_OFF);
        const float* bp = st ? bp2 : bp1;
        const float* xres = st ? x2 : x1;

        half8 a2w[2];
        #pragma unroll
        for (int ss = 0; ss < 2; ss++)
            a2w[ss] = *(const half8*)(&attT[st][((rt * 4 + kh2 * 2 + ss) * 64 + lane) * 8]);

        f32x4 y[8];
        #pragma unroll
        for (int c = 0; c < 8; c++) y[c] = f32x4{0,0,0,0};
        #pragma unroll
        for (int c = 0; c < 8; c++) {
            #pragma unroll
            for (int ss = 0; ss < 2; ss++) {
                half8 Wf = *(const half8*)(Wp + ((size_t)(((kh2 * 2 + ss) * 8 + c) * 64 + lane)) * 8);
                y[c] = mfma16(a2w[ss], Wf, y[c]);
            }
        }
        f32x4 (*partC)[2][8][64] = (f32x4(*)[2][8][64])&part[0][0][0][0];
        if (kh2 == 1) {
            #pragma unroll
            for (int c = 0; c < 8; c++) partC[rt][st][c][lane] = y[c];
        }
        __syncthreads();
        float yy[8][4];
        if (kh2 == 0) {
            float psum[4] = {0,0,0,0}, psq[4] = {0,0,0,0};
            #pragma unroll
            for (int c = 0; c < 8; c++) {
                f32x4 pp = partC[rt][st][c][lane];
                int n = c * 16 + ln;
                float bv = bp[n];
                #pragma unroll
                for (int r = 0; r < 4; r++) {
                    int m = rowG0 + rt * 16 + quad * 4 + r;
                    float v = y[c][r] + pp[r] + bv + xres[(size_t)m * D_ + n];
                    yy[c][r] = v; psum[r] += v; psq[r] += v * v;
                }
            }
            #pragma unroll
            for (int off = 1; off < 16; off <<= 1)
                #pragma unroll
                for (int r = 0; r < 4; r++) {
                    psum[r] += __shfl_xor(psum[r], off);
                    psq[r]  += __shfl_xor(psq[r], off);
                }
            if (ln == 0)
                #pragma unroll
                for (int r = 0; r < 4; r++) {
                    sstA[rt][quad * 4 + r][st][0] = psum[r];
                    sstA[rt][quad * 4 + r][st][1] = psq[r];
                }
        }
        __syncthreads();
        if (kh2 == 0) {
            #pragma unroll
            for (int r = 0; r < 4; r++) {
                int row = quad * 4 + r;
                float su = sstA[rt][row][0][0] + sstA[rt][row][1][0];
                float sq = sstA[rt][row][0][1] + sstA[rt][row][1][1];
                float mean = su * (1.f / 256.f);
                float var = sq * (1.f / 256.f) - mean * mean;
                float invs = rsqrtf(var + 1e-5f);
                int m = rowG0 + rt * 16 + row;
                int lt_m = m >> 4;
                #pragma unroll
                for (int c = 0; c < 8; c++) {
                    int colg = st * 128 + c * 16 + ln;
                    res[(size_t)m * D2_ + colg] = (_Float16)yy[c][r];
                    float yn = (yy[c][r] - mean) * invs * lnf_g[colg] + lnf_b[colg];
                    int s_x = colg >> 5, q_x = (colg >> 3) & 3, j = colg & 7;
                    xn[((size_t)((lt_m * 8 + s_x) * 64 + q_x * 16 + (m & 15))) * 8 + j] = (_Float16)yn;
                }
            }
        }
    }
}

// FUSED FFN: h = gelu(xn@Wf1+bf1) -> LDS (32 KB, never to global);
// y = h@Wf2+bf2+res; LN3 -> xt LDS; out = xt@Wo+bo. 512 thr, 32-row tiles.
__global__ __launch_bounds__(512) void ffn_kernel(const _Float16* xn, const _Float16* wsw,
        const float* bf1, const float* bf2, const _Float16* res,
        const float* g3, const float* b3, const float* bo, float* out) {
    __shared__ _Float16 hT[16384];       // 32 KB: 32 rows x 512 cols, FR layout
    __shared__ float sst[2][16][4][2];   // 1 KB
    __shared__ _Float16 xt[8192];        // 16 KB: 32 rows x 256 cols, FR layout
    __shared__ f32x4 pc[2][3][4][64];    // 24 KB: out-phase k partials (kh 1..3)
    int w = threadIdx.x >> 6, lane = threadIdx.x & 63;
    int quad = lane >> 4, ln = lane & 15;
    int rt = w & 1, nh = w >> 1;         // rt: row half (16 rows); nh: col quarter
    int mb = blockIdx.x * 32;
    int ltg = (mb + rt * 16) >> 4;       // global row-tile for this wave

    // ---- phase 1: h = gelu(xn @ Wf1 + bf1) -> hT ----
    {
        const _Float16* W = wsw + WF1_OFF;   // K=256, N=512, nc=32
        half8 a[8];
        #pragma unroll
        for (int s = 0; s < 8; s++)
            a[s] = *(const half8*)(xn + ((size_t)((ltg * 8 + s) * 64 + lane)) * 8);
        f32x4 acc[8];
        #pragma unroll
        for (int c = 0; c < 8; c++) acc[c] = f32x4{0,0,0,0};
        #pragma unroll
        for (int c = 0; c < 8; c++) {
            #pragma unroll
            for (int s = 0; s < 8; s++) {
                half8 Wf = *(const half8*)(W + ((size_t)((s * 32 + nh * 8 + c) * 64 + lane)) * 8);
                acc[c] = mfma16(a[s], Wf, acc[c]);
            }
        }
        #pragma unroll
        for (int c = 0; c < 8; c++) {
            int n = nh * 128 + c * 16 + ln;       // 0..511
            float bv = bf1[n];
            int s_h = n >> 5, q_h = (n >> 3) & 3, j = n & 7;
            #pragma unroll
            for (int r = 0; r < 4; r++) {
                float v = acc[c][r] + bv;
                float u = 0.7978845608f * (v + 0.044715f * v * v * v);
                float e = fexp2(-2.8853900818f * u);     // 2*log2(e)*u
                float ge = v * __builtin_amdgcn_rcpf(1.f + e);
                hT[((rt * 16 + s_h) * 64 + q_h * 16 + (quad * 4 + r)) * 8 + j] = (_Float16)ge;
            }
        }
    }
    __syncthreads();

    // ---- phase 2: y = hT @ Wf2 + bf2 + res ; LN3 -> xt ----
    float y[4][4];
    {
        const _Float16* W = wsw + WF2_OFF;   // K=512, N=256, nc=16
        f32x4 acc[4];
        #pragma unroll
        for (int c = 0; c < 4; c++) acc[c] = f32x4{0,0,0,0};
        #pragma unroll
        for (int s = 0; s < 16; s++) {
            half8 a = *(const half8*)(hT + ((size_t)((rt * 16 + s) * 64 + lane)) * 8);
            #pragma unroll
            for (int c = 0; c < 4; c++) {
                half8 Wf = *(const half8*)(W + ((size_t)((s * 16 + nh * 4 + c) * 64 + lane)) * 8);
                acc[c] = mfma16(a, Wf, acc[c]);
            }
        }
        float psum[4] = {0,0,0,0}, psq[4] = {0,0,0,0};
        #pragma unroll
        for (int c = 0; c < 4; c++) {
            int n = nh * 64 + c * 16 + ln;
            float bv = bf2[n];
            #pragma unroll
            for (int r = 0; r < 4; r++) {
                int m = mb + rt * 16 + quad * 4 + r;
                float v = acc[c][r] + bv + (float)res[(size_t)m * D2_ + n];
                y[c][r] = v; psum[r] += v; psq[r] += v * v;
            }
        }
        #pragma unroll
        for (int off = 1; off < 16; off <<= 1)
            #pragma unroll
            for (int r = 0; r < 4; r++) { psum[r] += __shfl_xor(psum[r], off); psq[r] += __shfl_xor(psq[r], off); }
        if (ln == 0)
            #pragma unroll
            for (int r = 0; r < 4; r++) { sst[rt][quad * 4 + r][nh][0] = psum[r]; sst[rt][quad * 4 + r][nh][1] = psq[r]; }
    }
    __syncthreads();
    #pragma unroll
    for (int r = 0; r < 4; r++) {
        int row = quad * 4 + r;
        float su = sst[rt][row][0][0] + sst[rt][row][1][0] + sst[rt][row][2][0] + sst[rt][row][3][0];
        float sq = sst[rt][row][0][1] + sst[rt][row][1][1] + sst[rt][row][2][1] + sst[rt][row][3][1];
        float mean = su * (1.f / 256.f);
        float var = sq * (1.f / 256.f) - mean * mean;
        float invs = rsqrtf(var + 1e-5f);
        #pragma unroll
        for (int c = 0; c < 4; c++) {
            int n = nh * 64 + c * 16 + ln;
            float yn = (y[c][r] - mean) * invs * g3[n] + b3[n];
            int s_x = n >> 5, q_x = (n >> 3) & 3, j = n & 7;
            xt[((rt * 8 + s_x) * 64 + q_x * 16 + row) * 8 + j] = (_Float16)yn;
        }
    }
    __syncthreads();

    // ---- phase 3: out = xt @ Wo + bo ; 4-way k-split over nh ----
    {
        int kh = nh;                          // 0..3, 2 s-chunks each
        const _Float16* Wo = wsw + WO_OFF;    // K=256, N=64(padded), nc=4
        f32x4 oacc[4];
        #pragma unroll
        for (int c = 0; c < 4; c++) oacc[c] = f32x4{0,0,0,0};
        #pragma unroll
        for (int ss = 0; ss < 2; ss++) {
            int s = kh * 2 + ss;
            half8 a = *(const half8*)(xt + ((size_t)((rt * 8 + s) * 64 + lane)) * 8);
            #pragma unroll
            for (int c = 0; c < 4; c++)
                oacc[c] = mfma16(a, *(const half8*)(Wo + ((size_t)((s * 4 + c) * 64 + lane)) * 8), oacc[c]);
        }
        if (kh > 0)
            #pragma unroll
            for (int c = 0; c < 4; c++) pc[rt][kh - 1][c][lane] = oacc[c];
        __syncthreads();
        if (kh == 0) {
            #pragma unroll
            for (int c = 0; c < 4; c++) {
                f32x4 p0 = pc[rt][0][c][lane];
                f32x4 p1 = pc[rt][1][c][lane];
                f32x4 p2 = pc[rt][2][c][lane];
                int n = c * 16 + ln;
                if (n < OUT_) {
                    float bv = bo[n];
                    #pragma unroll
                    for (int r = 0; r < 4; r++)
                        out[(size_t)(mb + rt * 16 + quad * 4 + r) * OUT_ + n]
                            = oacc[c][r] + p0[r] + p1[r] + p2[r] + bv;
                }
            }
        }
    }
}

extern "C" void kernel_launch(void* const* d_in, const int* in_sizes, int n_in,
                              void* d_out, int out_size, void* d_ws, size_t ws_size,
                              hipStream_t stream) {
    const float* x1    = (const float*)d_in[0];
    const float* x2    = (const float*)d_in[1];
    const float* ln1_g = (const float*)d_in[2];
    const float* ln1_b = (const float*)d_in[3];
    const float* ln2_g = (const float*)d_in[4];
    const float* ln2_b = (const float*)d_in[5];
    const float* Wq    = (const float*)d_in[6];
    const float* bq    = (const float*)d_in[7];
    const float* Wv1   = (const float*)d_in[8];
    const float* bv1   = (const float*)d_in[9];
    const float* Wk    = (const float*)d_in[10];
    const float* bk    = (const float*)d_in[11];
    const float* Wv2   = (const float*)d_in[12];
    const float* bv2   = (const float*)d_in[13];
    const float* Wp1   = (const float*)d_in[14];
    const float* bp1   = (const float*)d_in[15];
    const float* Wp2   = (const float*)d_in[16];
    const float* bp2   = (const float*)d_in[17];
    const float* lnf_g = (const float*)d_in[18];
    const float* lnf_b = (const float*)d_in[19];
    const float* Wf1   = (const float*)d_in[20];
    const float* bf1   = (const float*)d_in[21];
    const float* Wf2   = (const float*)d_in[22];
    const float* bf2   = (const float*)d_in[23];
    const float* ln3_g = (const float*)d_in[24];
    const float* ln3_b = (const float*)d_in[25];
    const float* Wo    = (const float*)d_in[26];
    const float* bo    = (const float*)d_in[27];
    float* out = (float*)d_out;

    char* ws = (char*)d_ws;
    const size_t MB = 1 << 20;
    _Float16* q1sw   = (_Float16*)(ws + 0 * MB);    // 4 MB
    _Float16* k2sw   = (_Float16*)(ws + 4 * MB);    // 4 MB
    unsigned char* vsw8 = (unsigned char*)(ws + 8 * MB);   // 4 MB (fp8 Vcat per batch)
    _Float16* wsw    = (_Float16*)(ws + 28 * MB);   // ~0.74 MB
    float*    rowsum = (float*)   (ws + 29 * MB);   // 64 KB
    _Float16* res    = (_Float16*)(ws + 30 * MB);   // 8 MB
    _Float16* xn     = (_Float16*)(ws + 46 * MB);   // 8 MB
    unsigned char* pmat8 = (unsigned char*)(ws + 78 * MB); // 64 MB (fp8 P per batch)

    prep_kernel<<<dim3(512, 10), 256, 0, stream>>>(Wq, Wv1, Wk, Wv2, Wp1, Wp2, Wf1, Wf2, Wo,
                                                   wsw, rowsum);
    proj_kernel<<<dim3(M_ / 64, 2), 256, 0, stream>>>(x1, x2, wsw,
                                                      ln1_g, ln1_b, ln2_g, ln2_b,
                                                      bq, bv1, bk, bv2,
                                                      q1sw, k2sw, vsw8);
    score_kernel<<<dim3(32, 32, 4), 256, 0, stream>>>(q1sw, k2sw, pmat8, rowsum);
    pv_kernel<<<dim3(M_ / 32), 512, 0, stream>>>(pmat8, vsw8, rowsum, wsw,
                                                 bp1, bp2, x1, x2, lnf_g, lnf_b,
                                                 res, xn);
    ffn_kernel<<<dim3(M_ / 32), 512, 0, stream>>>(xn, wsw, bf1, bf2, res,
                                                  ln3_g, ln3_b, bo, out);
}

// Round 9
// 224.570 us; speedup vs baseline: 1.0107x; 1.0107x over previous
//
#include <hip/hip_runtime.h>
#include <hip/hip_fp16.h>

typedef _Float16 half8 __attribute__((ext_vector_type(8)));
typedef _Float16 half4 __attribute__((ext_vector_type(4)));
typedef float f32x4 __attribute__((ext_vector_type(4)));
typedef float f32x16 __attribute__((ext_vector_type(16)));
typedef int  i32x8 __attribute__((ext_vector_type(8)));

#define B_   4
#define L_   4096
#define D_   128
#define M_   (B_*L_)     // 16384
#define D2_  256
#define H_   512
#define OUT_ 55

__device__ __forceinline__ f32x4 mfma16(half8 a, half8 b, f32x4 c) {
    return __builtin_amdgcn_mfma_f32_16x16x32_f16(a, b, c, 0, 0, 0);
}
// MX-scaled fp8 MFMA, 32x32x64, unit scales (E8M0 127 = 1.0). fmt 0 = OCP e4m3.
__device__ __forceinline__ f32x16 mfma_mx32(i32x8 a, i32x8 b, f32x16 c) {
    return __builtin_amdgcn_mfma_scale_f32_32x32x64_f8f6f4(a, b, c, 0, 0, 0, 127, 0, 127);
}
// pack 4 floats -> 4 fp8 e4m3 bytes (OCP on gfx950)
__device__ __forceinline__ int pk4(float a, float b, float c, float d) {
    int t = __builtin_amdgcn_cvt_pk_fp8_f32(a, b, 0, false);
    return __builtin_amdgcn_cvt_pk_fp8_f32(c, d, t, true);
}
__device__ __forceinline__ float fexp2(float x) { return __builtin_amdgcn_exp2f(x); }

// fold softmax scale (1/sqrt(128)) * log2(e) into k2 so score uses bare v_exp
#define KSCL (0.08838834764831845f * 1.4426950408889634f)

// ---- weight swizzle offsets (in halfs) within wsw region ----
#define WQ_OFF   0
#define WV1_OFF  16384
#define WK_OFF   32768
#define WV2_OFF  49152
#define WP1_OFF  65536
#define WP2_OFF  81920
#define WF1_OFF  98304     // 256x512 = 131072
#define WF2_OFF  229376    // 512x256 = 131072
#define WO_OFF   360448    // 256x64 (padded) = 16384

// ---- shared 64-k-chunk fragment map for the MX 32x32x64 path ----
// hw position (g = lane>>5, byte j=0..31) -> logical k = 16*i + 4*(2g+jh) + r
// with j = 16*jh + 4*i + r.  P (score) and V (proj) both write this map;
// pv consumes both, so any hw-internal k-order cancels (A/B mirror).
// Memory: P per batch  [att32(128)][k64(64)][lane64][32B] = 16 MB
//         V per batch  [k64(64)][vcol32(8)][lane64][32B]  =  1 MB
// lane64 = (row-within-32-tile) + 32*g.
// Prefetch-depth ledger (pv phase A): depth-2 = 48.0us (r6), depth-4 = 46.4us
// (r7, BEST), depth-6 = 56.4us (r8 — register-shuffle chains dominate).
// Keep depth 4 for P, 2 for V.

__global__ void prep_kernel(const float* Wq, const float* Wv1, const float* Wk,
                            const float* Wv2, const float* Wp1, const float* Wp2,
                            const float* Wf1, const float* Wf2, const float* Wo,
                            _Float16* wsw, float* rowsum) {
    int id = blockIdx.y;
    int t  = blockIdx.x * 256 + threadIdx.x;
    if (id == 9) {
        if (t < 4096) ((f32x4*)rowsum)[t] = f32x4{0.f, 0.f, 0.f, 0.f};
        return;
    }
    const float* src = nullptr; int K = 0, N = 0, Npad = 0, off = 0;
    switch (id) {
        case 0: src = Wq;  K = 128; N = 128; Npad = 128; off = WQ_OFF;  break;
        case 1: src = Wv1; K = 128; N = 128; Npad = 128; off = WV1_OFF; break;
        case 2: src = Wk;  K = 128; N = 128; Npad = 128; off = WK_OFF;  break;
        case 3: src = Wv2; K = 128; N = 128; Npad = 128; off = WV2_OFF; break;
        case 4: src = Wp1; K = 128; N = 128; Npad = 128; off = WP1_OFF; break;
        case 5: src = Wp2; K = 128; N = 128; Npad = 128; off = WP2_OFF; break;
        case 6: src = Wf1; K = 256; N = 512; Npad = 512; off = WF1_OFF; break;
        case 7: src = Wf2; K = 512; N = 256; Npad = 256; off = WF2_OFF; break;
        case 8: src = Wo;  K = 256; N = 55;  Npad = 64;  off = WO_OFF;  break;
        default: return;
    }
    int total = K * Npad;
    if (t >= total) return;
    int k = t / Npad, n = t % Npad;
    float v = (n < N) ? src[k * N + n] : 0.f;
    int s = k >> 5, c = n >> 4, ln = n & 15;
    int q, j;
    if (id == 4 || id == 5) { q = (k >> 2) & 3; j = (k & 3) + (((k >> 4) & 1) << 2); }
    else                    { q = (k >> 3) & 3; j = k & 7; }
    int nc = Npad >> 4;
    wsw[off + ((size_t)((s * nc + c) * 64 + q * 16 + ln)) * 8 + j] = (_Float16)v;
}

// FR layout for X[M][C] halfs:
// idx = ((lt*(C/32) + s)*64 + q*16 + ln_r)*8 + j ; lt=row>>4, ln_r=row&15,
// s=col>>5, q=(col>>3)&3, j=col&7.

__global__ __launch_bounds__(256) void proj_kernel(const float* x1, const float* x2,
        const _Float16* wsw,
        const float* ln1_g, const float* ln1_b, const float* ln2_g, const float* ln2_b,
        const float* bq, const float* bv1, const float* bk, const float* bv2,
        _Float16* q1, _Float16* k2, unsigned char* vsw8) {
    int g2 = blockIdx.y;  // 0: stream 1, 1: stream 2
    const float* X  = g2 ? x2 : x1;
    const float* lg = g2 ? ln2_g : ln1_g;
    const float* lb = g2 ? ln2_b : ln1_b;
    int wave = threadIdx.x >> 6, lane = threadIdx.x & 63;
    int quad = lane >> 4, ln = lane & 15;
    int mbase = blockIdx.x * 64 + wave * 16;
    int lt = mbase >> 4;

    // ---- fused LN: this lane holds row (mbase+ln), cols s*32+quad*8..+7 ----
    const float* xr = X + (size_t)(mbase + ln) * D_;
    float xv[4][8];
    float sum = 0.f, sq = 0.f;
    #pragma unroll
    for (int s = 0; s < 4; s++) {
        f32x4 v0 = *(const f32x4*)(xr + s * 32 + quad * 8);
        f32x4 v1 = *(const f32x4*)(xr + s * 32 + quad * 8 + 4);
        #pragma unroll
        for (int j = 0; j < 4; j++) {
            xv[s][j]     = v0[j];
            xv[s][j + 4] = v1[j];
            sum += v0[j] + v1[j];
            sq  += v0[j] * v0[j] + v1[j] * v1[j];
        }
    }
    sum += __shfl_xor(sum, 16); sum += __shfl_xor(sum, 32);
    sq  += __shfl_xor(sq, 16);  sq  += __shfl_xor(sq, 32);
    float mean = sum * (1.f / 128.f);
    float var  = sq * (1.f / 128.f) - mean * mean;
    float inv  = rsqrtf(var + 1e-5f);
    half8 a[4];
    #pragma unroll
    for (int s = 0; s < 4; s++) {
        f32x4 g0 = *(const f32x4*)(lg + s * 32 + quad * 8);
        f32x4 g1 = *(const f32x4*)(lg + s * 32 + quad * 8 + 4);
        f32x4 b0 = *(const f32x4*)(lb + s * 32 + quad * 8);
        f32x4 b1 = *(const f32x4*)(lb + s * 32 + quad * 8 + 4);
        #pragma unroll
        for (int j = 0; j < 4; j++) {
            a[s][j]     = (_Float16)((xv[s][j] - mean) * inv * g0[j] + b0[j]);
            a[s][j + 4] = (_Float16)((xv[s][j + 4] - mean) * inv * g1[j] + b1[j]);
        }
    }

    // ---- pipeline 0: Q/K projection -> fp16 FR ----
    {
        const _Float16* Bw = wsw + (g2 ? WK_OFF : WQ_OFF);
        const float* bias = g2 ? bk : bq;
        float scl = g2 ? KSCL : 1.f;
        _Float16* out = g2 ? k2 : q1;
        f32x4 acc[8];
        #pragma unroll
        for (int c = 0; c < 8; c++) acc[c] = f32x4{0.f, 0.f, 0.f, 0.f};
        half8 Wc[4], Wn[4];
        #pragma unroll
        for (int s = 0; s < 4; s++)
            Wc[s] = *(const half8*)(Bw + ((size_t)((s * 8 + 0) * 64 + lane)) * 8);
        #pragma unroll
        for (int c = 0; c < 8; c++) {
            int cn = (c < 7) ? c + 1 : 7;
            #pragma unroll
            for (int s = 0; s < 4; s++)
                Wn[s] = *(const half8*)(Bw + ((size_t)((s * 8 + cn) * 64 + lane)) * 8);
            #pragma unroll
            for (int s = 0; s < 4; s++)
                acc[c] = mfma16(a[s], Wc[s], acc[c]);
            #pragma unroll
            for (int s = 0; s < 4; s++) Wc[s] = Wn[s];
        }
        #pragma unroll
        for (int c = 0; c < 8; c++) {
            int n = c * 16 + ln;
            float bv = bias[n];
            #pragma unroll
            for (int r = 0; r < 4; r++) {
                int s_o = c >> 1, q_o = ((c & 1) << 1) | (ln >> 3), j = ln & 7;
                out[((size_t)((lt * 4 + s_o) * 64 + q_o * 16 + (quad * 4 + r))) * 8 + j]
                    = (_Float16)((acc[c][r] + bv) * scl);
            }
        }
    }

    // ---- pipeline 1: V projection -> fp8, MX 32x32x64 A-fragment layout ----
    {
        const _Float16* Bw = wsw + (g2 ? WV2_OFF : WV1_OFF);
        const float* bias = g2 ? bv2 : bv1;
        int cbase = g2 ? 8 : 0;
        f32x4 acc[8];
        #pragma unroll
        for (int c = 0; c < 8; c++) acc[c] = f32x4{0.f, 0.f, 0.f, 0.f};
        half8 Wc[4], Wn[4];
        #pragma unroll
        for (int s = 0; s < 4; s++)
            Wc[s] = *(const half8*)(Bw + ((size_t)((s * 8 + 0) * 64 + lane)) * 8);
        #pragma unroll
        for (int c = 0; c < 8; c++) {
            int cn = (c < 7) ? c + 1 : 7;
            #pragma unroll
            for (int s = 0; s < 4; s++)
                Wn[s] = *(const half8*)(Bw + ((size_t)((s * 8 + cn) * 64 + lane)) * 8);
            #pragma unroll
            for (int s = 0; s < 4; s++)
                acc[c] = mfma16(a[s], Wc[s], acc[c]);
            #pragma unroll
            for (int s = 0; s < 4; s++) Wc[s] = Wn[s];
        }
        // k position of acc[c][r] within its 64-k chunk: 16*wave + 4*quad + r
        // -> i = wave, g = quad>>1, jh = quad&1, byte = 16*jh + 4*i + r.
        int b = mbase >> 12;
        int k64 = (mbase & (L_ - 1)) >> 6;       // = blockIdx.x & 63
        int gg = quad >> 1, jh = quad & 1;
        unsigned char* Vb = vsw8 + (size_t)b * (1u << 20);
        #pragma unroll
        for (int c = 0; c < 8; c++) {
            int n = c * 16 + ln;
            float bv = bias[n];
            int pk = pk4(acc[c][0] + bv, acc[c][1] + bv, acc[c][2] + bv, acc[c][3] + bv);
            int v32 = (cbase + c) >> 1;                       // vcol 32-tile (0..7)
            int lane32 = ((c & 1) << 4) + ln + 32 * gg;       // row-in-tile + 32g
            *(int*)(Vb + ((size_t)((k64 * 8 + v32) * 64 + lane32)) * 32 + 16 * jh + 4 * wave) = pk;
        }
    }
}

// Pass 1: S^T tiles (A=q1 rows = softmax k-dim, B=k2^T cols = att rows).
// 16x16 MFMA kept; P store addresses target the MX 32x32x64 B-fragment layout.
// XCD-aware block swizzle: each XCD works a contiguous q1-row band.
__global__ __launch_bounds__(256) void score_kernel(
        const _Float16* __restrict__ q1sw, const _Float16* __restrict__ k2sw,
        unsigned char* __restrict__ pmat8, float* __restrict__ rowsum) {
    int w = threadIdx.x >> 6, lane = threadIdx.x & 63;
    int quad = lane >> 4, ln = lane & 15;
    int b = blockIdx.z;
    int id0 = blockIdx.y * 32 + blockIdx.x;        // 0..1023 within batch
    int id  = ((id0 & 7) << 7) + (id0 >> 3);       // bijective XCD chunking
    int bx = id & 31, by = id >> 5;
    int kL0 = by * 128 + (w & 1) * 64;             // q1 rows (contraction dim of PV)
    int mL0 = bx * 128 + (w >> 1) * 64;            // k2 rows (att rows)
    int ltk = ((b << 12) + kL0) >> 4;
    int ltm = ((b << 12) + mL0) >> 4;

    f32x4 acc[4][4];
    #pragma unroll
    for (int i = 0; i < 4; i++)
        #pragma unroll
        for (int j = 0; j < 4; j++) acc[i][j] = f32x4{0.f, 0.f, 0.f, 0.f};

    #pragma unroll
    for (int s = 0; s < 4; s++) {
        half8 a[4], bq[4];
        #pragma unroll
        for (int i = 0; i < 4; i++)
            a[i] = *(const half8*)(q1sw + ((size_t)(((ltk + i) * 4 + s) * 64 + lane)) * 8);
        #pragma unroll
        for (int j = 0; j < 4; j++)
            bq[j] = *(const half8*)(k2sw + ((size_t)(((ltm + j) * 4 + s) * 64 + lane)) * 8);
        #pragma unroll
        for (int i = 0; i < 4; i++)
            #pragma unroll
            for (int j = 0; j < 4; j++)
                acc[i][j] = mfma16(a[i], bq[j], acc[i][j]);
    }

    unsigned char* Pb = pmat8 + (size_t)b * (16u << 20);
    int k64 = kL0 >> 6;
    int gg = quad >> 1, jh = quad & 1;
    #pragma unroll
    for (int j = 0; j < 4; j++) {
        int4 d;
        float csum = 0.f;
        #pragma unroll
        for (int i = 0; i < 4; i++) {
            float p0 = fexp2(acc[i][j][0]);
            float p1 = fexp2(acc[i][j][1]);
            float p2 = fexp2(acc[i][j][2]);
            float p3 = fexp2(acc[i][j][3]);
            csum += (p0 + p1) + (p2 + p3);
            ((int*)&d)[i] = pk4(p0, p1, p2, p3);   // byte 4i+r -> k 16i+4*quad+r
        }
        csum += __shfl_xor(csum, 16);
        csum += __shfl_xor(csum, 32);
        if (lane < 16)
            atomicAdd(&rowsum[(b << 12) + mL0 + j * 16 + ln], csum);
        int att32 = (mL0 >> 5) + (j >> 1);
        int a32 = ((j & 1) << 4) + ln;             // att row within 32-tile
        *(int4*)(Pb + ((size_t)((att32 * 64 + k64) * 64 + a32 + 32 * gg)) * 32 + 16 * jh) = d;
    }
}

// Pass 2 FUSED: pv + attn_out.
// Phase A: O^T = V^T.P^T, MX fp8 32x32x64, 8 waves (wc, kh), k-half partials
// merged in 32 KB LDS. P ring depth 4 (HBM/L3 stream), V double-buffer (L2)
// — the measured-best depth (see ledger at top). setprio around MFMA cluster;
// XCD-aware block swizzle.
// Phase B: normalized fp16 O-tile -> 16 KB LDS attT (FR, block-local rows).
// Phase C: out_s = att_s @ Wp_s + bias + residual; LNf -> res, xn.
__global__ __launch_bounds__(512) void pv_kernel(
        const unsigned char* __restrict__ pmat8, const unsigned char* __restrict__ vsw8,
        const float* __restrict__ rowsum, const _Float16* __restrict__ wsw,
        const float* bp1, const float* bp2,
        const float* x1, const float* x2, const float* lnf_g, const float* lnf_b,
        _Float16* __restrict__ res, _Float16* __restrict__ xn) {
    __shared__ f32x4 part[4][2][4][64];   // 32 KB: [wc][t][q][lane]; reused in C
    __shared__ _Float16 attT[2][4096];    // 16 KB: per stream, 32 rows x 128 cols FR
    __shared__ float sstA[2][16][2][2];   // 1 KB: LNf cross-stream stats
    int w = threadIdx.x >> 6, lane = threadIdx.x & 63;
    int quad = lane >> 4, ln = lane & 15;
    int wc = w & 3, kh = w >> 2;
    int id0 = blockIdx.x;                          // 0..511
    int bid = ((id0 & 7) << 6) + (id0 >> 3);       // bijective XCD chunking
    int rowG0 = bid * 32;
    int b = rowG0 >> 12;
    int att32 = (rowG0 & (L_ - 1)) >> 5;
    const unsigned char* Pb = pmat8 + (size_t)b * (16u << 20);
    const unsigned char* Vb = vsw8 + (size_t)b * (1u << 20);

    const unsigned char* Vbase = Vb + (size_t)(wc * 2) * 2048 + (size_t)lane * 32;
    const unsigned char* Pbase = Pb + (size_t)att32 * 131072 + (size_t)lane * 32;
    int sp0 = kh * 32;

    f32x16 acc0, acc1;
    #pragma unroll
    for (int i = 0; i < 16; i++) { acc0[i] = 0.f; acc1[i] = 0.f; }

    #define VLOAD2(dA, dB, sp) do {                                           \
        dA = *(const i32x8*)(Vbase + (size_t)(sp) * 16384);                   \
        dB = *(const i32x8*)(Vbase + (size_t)(sp) * 16384 + 2048);            \
    } while (0)
    #define PLOAD(dP, sp) do {                                                \
        dP = *(const i32x8*)(Pbase + (size_t)(sp) * 2048);                    \
    } while (0)

    i32x8 a0, b0, a1, b1, na, nb;
    i32x8 p0, p1, p2, p3, np;
    VLOAD2(a0, b0, sp0);
    VLOAD2(a1, b1, sp0 + 1);
    PLOAD(p0, sp0);
    PLOAD(p1, sp0 + 1);
    PLOAD(p2, sp0 + 2);
    PLOAD(p3, sp0 + 3);
    for (int ii = 0; ii < 32; ii += 2) {
        int s2 = sp0 + ((ii + 2 < 32) ? ii + 2 : 30);
        int s3 = sp0 + ((ii + 3 < 32) ? ii + 3 : 31);
        int s4 = sp0 + ((ii + 4 < 32) ? ii + 4 : 31);
        int s5 = sp0 + ((ii + 5 < 32) ? ii + 5 : 31);
        VLOAD2(na, nb, s2);
        PLOAD(np, s4);
        __builtin_amdgcn_s_setprio(1);
        acc0 = mfma_mx32(a0, p0, acc0);
        acc1 = mfma_mx32(b0, p0, acc1);
        __builtin_amdgcn_s_setprio(0);
        a0 = na; b0 = nb;
        p0 = p1; p1 = p2; p2 = p3; p3 = np;
        VLOAD2(na, nb, s3);
        PLOAD(np, s5);
        __builtin_amdgcn_s_setprio(1);
        acc0 = mfma_mx32(a1, p0, acc0);
        acc1 = mfma_mx32(b1, p0, acc1);
        __builtin_amdgcn_s_setprio(0);
        a1 = na; b1 = nb;
        p0 = p1; p1 = p2; p2 = p3; p3 = np;
    }
    #undef VLOAD2
    #undef PLOAD

    if (kh == 1) {
        #pragma unroll
        for (int q = 0; q < 4; q++) {
            part[wc][0][q][lane] = f32x4{acc0[q * 4 + 0], acc0[q * 4 + 1],
                                         acc0[q * 4 + 2], acc0[q * 4 + 3]};
            part[wc][1][q][lane] = f32x4{acc1[q * 4 + 0], acc1[q * 4 + 1],
                                         acc1[q * 4 + 2], acc1[q * 4 + 3]};
        }
    }
    __syncthreads();
    if (kh == 0) {
        // D: col = att row = lane&31 ; row = Vcol-in-tile = (reg&3)+8*(reg>>2)+4*g
        int rowL = lane & 31;
        float inv = 1.f / rowsum[rowG0 + rowL];
        int g = lane >> 5;
        int ltl = rowL >> 4, lnr = lane & 15;
        #pragma unroll
        for (int t = 0; t < 2; t++) {
            int v32 = wc * 2 + t;
            int stw = (v32 >= 4);
            int s = v32 & 3;
            #pragma unroll
            for (int q = 0; q < 4; q++) {
                f32x4 pp = part[wc][t][q][lane];
                half4 hv;
                #pragma unroll
                for (int rr = 0; rr < 4; rr++) {
                    float v = ((t == 0) ? acc0[q * 4 + rr] : acc1[q * 4 + rr]) + pp[rr];
                    hv[rr] = (_Float16)(v * inv);
                }
                // FR (block-local rows): j = 4g + rr
                *(half4*)(&attT[stw][((ltl * 4 + s) * 64 + q * 16 + lnr) * 8 + 4 * g]) = hv;
            }
        }
    }
    __syncthreads();

    // ---- phase C: att @ Wp + bias + residual ; LNf -> res, xn ----
    {
        int rt = w & 1, st = (w >> 1) & 1, kh2 = w >> 2;
        const _Float16* Wp = wsw + (st ? WP2_OFF : WP1_OFF);
        const float* bp = st ? bp2 : bp1;
        const float* xres = st ? x2 : x1;

        half8 a2w[2];
        #pragma unroll
        for (int ss = 0; ss < 2; ss++)
            a2w[ss] = *(const half8*)(&attT[st][((rt * 4 + kh2 * 2 + ss) * 64 + lane) * 8]);

        f32x4 y[8];
        #pragma unroll
        for (int c = 0; c < 8; c++) y[c] = f32x4{0,0,0,0};
        #pragma unroll
        for (int c = 0; c < 8; c++) {
            #pragma unroll
            for (int ss = 0; ss < 2; ss++) {
                half8 Wf = *(const half8*)(Wp + ((size_t)(((kh2 * 2 + ss) * 8 + c) * 64 + lane)) * 8);
                y[c] = mfma16(a2w[ss], Wf, y[c]);
            }
        }
        f32x4 (*partC)[2][8][64] = (f32x4(*)[2][8][64])&part[0][0][0][0];
        if (kh2 == 1) {
            #pragma unroll
            for (int c = 0; c < 8; c++) partC[rt][st][c][lane] = y[c];
        }
        __syncthreads();
        float yy[8][4];
        if (kh2 == 0) {
            float psum[4] = {0,0,0,0}, psq[4] = {0,0,0,0};
            #pragma unroll
            for (int c = 0; c < 8; c++) {
                f32x4 pp = partC[rt][st][c][lane];
                int n = c * 16 + ln;
                float bv = bp[n];
                #pragma unroll
                for (int r = 0; r < 4; r++) {
                    int m = rowG0 + rt * 16 + quad * 4 + r;
                    float v = y[c][r] + pp[r] + bv + xres[(size_t)m * D_ + n];
                    yy[c][r] = v; psum[r] += v; psq[r] += v * v;
                }
            }
            #pragma unroll
            for (int off = 1; off < 16; off <<= 1)
                #pragma unroll
                for (int r = 0; r < 4; r++) {
                    psum[r] += __shfl_xor(psum[r], off);
                    psq[r]  += __shfl_xor(psq[r], off);
                }
            if (ln == 0)
                #pragma unroll
                for (int r = 0; r < 4; r++) {
                    sstA[rt][quad * 4 + r][st][0] = psum[r];
                    sstA[rt][quad * 4 + r][st][1] = psq[r];
                }
        }
        __syncthreads();
        if (kh2 == 0) {
            #pragma unroll
            for (int r = 0; r < 4; r++) {
                int row = quad * 4 + r;
                float su = sstA[rt][row][0][0] + sstA[rt][row][1][0];
                float sq = sstA[rt][row][0][1] + sstA[rt][row][1][1];
                float mean = su * (1.f / 256.f);
                float var = sq * (1.f / 256.f) - mean * mean;
                float invs = rsqrtf(var + 1e-5f);
                int m = rowG0 + rt * 16 + row;
                int lt_m = m >> 4;
                #pragma unroll
                for (int c = 0; c < 8; c++) {
                    int colg = st * 128 + c * 16 + ln;
                    res[(size_t)m * D2_ + colg] = (_Float16)yy[c][r];
                    float yn = (yy[c][r] - mean) * invs * lnf_g[colg] + lnf_b[colg];
                    int s_x = colg >> 5, q_x = (colg >> 3) & 3, j = colg & 7;
                    xn[((size_t)((lt_m * 8 + s_x) * 64 + q_x * 16 + (m & 15))) * 8 + j] = (_Float16)yn;
                }
            }
        }
    }
}

// FUSED FFN: h = gelu(xn@Wf1+bf1) -> LDS (32 KB, never to global);
// y = h@Wf2+bf2+res; LN3 -> xt LDS; out = xt@Wo+bo. 512 thr, 32-row tiles.
__global__ __launch_bounds__(512) void ffn_kernel(const _Float16* xn, const _Float16* wsw,
        const float* bf1, const float* bf2, const _Float16* res,
        const float* g3, const float* b3, const float* bo, float* out) {
    __shared__ _Float16 hT[16384];       // 32 KB: 32 rows x 512 cols, FR layout
    __shared__ float sst[2][16][4][2];   // 1 KB
    __shared__ _Float16 xt[8192];        // 16 KB: 32 rows x 256 cols, FR layout
    __shared__ f32x4 pc[2][3][4][64];    // 24 KB: out-phase k partials (kh 1..3)
    int w = threadIdx.x >> 6, lane = threadIdx.x & 63;
    int quad = lane >> 4, ln = lane & 15;
    int rt = w & 1, nh = w >> 1;         // rt: row half (16 rows); nh: col quarter
    int mb = blockIdx.x * 32;
    int ltg = (mb + rt * 16) >> 4;       // global row-tile for this wave

    // ---- phase 1: h = gelu(xn @ Wf1 + bf1) -> hT ----
    {
        const _Float16* W = wsw + WF1_OFF;   // K=256, N=512, nc=32
        half8 a[8];
        #pragma unroll
        for (int s = 0; s < 8; s++)
            a[s] = *(const half8*)(xn + ((size_t)((ltg * 8 + s) * 64 + lane)) * 8);
        f32x4 acc[8];
        #pragma unroll
        for (int c = 0; c < 8; c++) acc[c] = f32x4{0,0,0,0};
        #pragma unroll
        for (int c = 0; c < 8; c++) {
            #pragma unroll
            for (int s = 0; s < 8; s++) {
                half8 Wf = *(const half8*)(W + ((size_t)((s * 32 + nh * 8 + c) * 64 + lane)) * 8);
                acc[c] = mfma16(a[s], Wf, acc[c]);
            }
        }
        #pragma unroll
        for (int c = 0; c < 8; c++) {
            int n = nh * 128 + c * 16 + ln;       // 0..511
            float bv = bf1[n];
            int s_h = n >> 5, q_h = (n >> 3) & 3, j = n & 7;
            #pragma unroll
            for (int r = 0; r < 4; r++) {
                float v = acc[c][r] + bv;
                float u = 0.7978845608f * (v + 0.044715f * v * v * v);
                float e = fexp2(-2.8853900818f * u);     // 2*log2(e)*u
                float ge = v * __builtin_amdgcn_rcpf(1.f + e);
                hT[((rt * 16 + s_h) * 64 + q_h * 16 + (quad * 4 + r)) * 8 + j] = (_Float16)ge;
            }
        }
    }
    __syncthreads();

    // ---- phase 2: y = hT @ Wf2 + bf2 + res ; LN3 -> xt ----
    float y[4][4];
    {
        const _Float16* W = wsw + WF2_OFF;   // K=512, N=256, nc=16
        f32x4 acc[4];
        #pragma unroll
        for (int c = 0; c < 4; c++) acc[c] = f32x4{0,0,0,0};
        #pragma unroll
        for (int s = 0; s < 16; s++) {
            half8 a = *(const half8*)(hT + ((size_t)((rt * 16 + s) * 64 + lane)) * 8);
            #pragma unroll
            for (int c = 0; c < 4; c++) {
                half8 Wf = *(const half8*)(W + ((size_t)((s * 16 + nh * 4 + c) * 64 + lane)) * 8);
                acc[c] = mfma16(a, Wf, acc[c]);
            }
        }
        float psum[4] = {0,0,0,0}, psq[4] = {0,0,0,0};
        #pragma unroll
        for (int c = 0; c < 4; c++) {
            int n = nh * 64 + c * 16 + ln;
            float bv = bf2[n];
            #pragma unroll
            for (int r = 0; r < 4; r++) {
                int m = mb + rt * 16 + quad * 4 + r;
                float v = acc[c][r] + bv + (float)res[(size_t)m * D2_ + n];
                y[c][r] = v; psum[r] += v; psq[r] += v * v;
            }
        }
        #pragma unroll
        for (int off = 1; off < 16; off <<= 1)
            #pragma unroll
            for (int r = 0; r < 4; r++) { psum[r] += __shfl_xor(psum[r], off); psq[r] += __shfl_xor(psq[r], off); }
        if (ln == 0)
            #pragma unroll
            for (int r = 0; r < 4; r++) { sst[rt][quad * 4 + r][nh][0] = psum[r]; sst[rt][quad * 4 + r][nh][1] = psq[r]; }
    }
    __syncthreads();
    #pragma unroll
    for (int r = 0; r < 4; r++) {
        int row = quad * 4 + r;
        float su = sst[rt][row][0][0] + sst[rt][row][1][0] + sst[rt][row][2][0] + sst[rt][row][3][0];
        float sq = sst[rt][row][0][1] + sst[rt][row][1][1] + sst[rt][row][2][1] + sst[rt][row][3][1];
        float mean = su * (1.f / 256.f);
        float var = sq * (1.f / 256.f) - mean * mean;
        float invs = rsqrtf(var + 1e-5f);
        #pragma unroll
        for (int c = 0; c < 4; c++) {
            int n = nh * 64 + c * 16 + ln;
            float yn = (y[c][r] - mean) * invs * g3[n] + b3[n];
            int s_x = n >> 5, q_x = (n >> 3) & 3, j = n & 7;
            xt[((rt * 8 + s_x) * 64 + q_x * 16 + row) * 8 + j] = (_Float16)yn;
        }
    }
    __syncthreads();

    // ---- phase 3: out = xt @ Wo + bo ; 4-way k-split over nh ----
    {
        int kh = nh;                          // 0..3, 2 s-chunks each
        const _Float16* Wo = wsw + WO_OFF;    // K=256, N=64(padded), nc=4
        f32x4 oacc[4];
        #pragma unroll
        for (int c = 0; c < 4; c++) oacc[c] = f32x4{0,0,0,0};
        #pragma unroll
        for (int ss = 0; ss < 2; ss++) {
            int s = kh * 2 + ss;
            half8 a = *(const half8*)(xt + ((size_t)((rt * 8 + s) * 64 + lane)) * 8);
            #pragma unroll
            for (int c = 0; c < 4; c++)
                oacc[c] = mfma16(a, *(const half8*)(Wo + ((size_t)((s * 4 + c) * 64 + lane)) * 8), oacc[c]);
        }
        if (kh > 0)
            #pragma unroll
            for (int c = 0; c < 4; c++) pc[rt][kh - 1][c][lane] = oacc[c];
        __syncthreads();
        if (kh == 0) {
            #pragma unroll
            for (int c = 0; c < 4; c++) {
                f32x4 p0 = pc[rt][0][c][lane];
                f32x4 p1 = pc[rt][1][c][lane];
                f32x4 p2 = pc[rt][2][c][lane];
                int n = c * 16 + ln;
                if (n < OUT_) {
                    float bv = bo[n];
                    #pragma unroll
                    for (int r = 0; r < 4; r++)
                        out[(size_t)(mb + rt * 16 + quad * 4 + r) * OUT_ + n]
                            = oacc[c][r] + p0[r] + p1[r] + p2[r] + bv;
                }
            }
        }
    }
}

extern "C" void kernel_launch(void* const* d_in, const int* in_sizes, int n_in,
                              void* d_out, int out_size, void* d_ws, size_t ws_size,
                              hipStream_t stream) {
    const float* x1    = (const float*)d_in[0];
    const float* x2    = (const float*)d_in[1];
    const float* ln1_g = (const float*)d_in[2];
    const float* ln1_b = (const float*)d_in[3];
    const float* ln2_g = (const float*)d_in[4];
    const float* ln2_b = (const float*)d_in[5];
    const float* Wq    = (const float*)d_in[6];
    const float* bq    = (const float*)d_in[7];
    const float* Wv1   = (const float*)d_in[8];
    const float* bv1   = (const float*)d_in[9];
    const float* Wk    = (const float*)d_in[10];
    const float* bk    = (const float*)d_in[11];
    const float* Wv2   = (const float*)d_in[12];
    const float* bv2   = (const float*)d_in[13];
    const float* Wp1   = (const float*)d_in[14];
    const float* bp1   = (const float*)d_in[15];
    const float* Wp2   = (const float*)d_in[16];
    const float* bp2   = (const float*)d_in[17];
    const float* lnf_g = (const float*)d_in[18];
    const float* lnf_b = (const float*)d_in[19];
    const float* Wf1   = (const float*)d_in[20];
    const float* bf1   = (const float*)d_in[21];
    const float* Wf2   = (const float*)d_in[22];
    const float* bf2   = (const float*)d_in[23];
    const float* ln3_g = (const float*)d_in[24];
    const float* ln3_b = (const float*)d_in[25];
    const float* Wo    = (const float*)d_in[26];
    const float* bo    = (const float*)d_in[27];
    float* out = (float*)d_out;

    char* ws = (char*)d_ws;
    const size_t MB = 1 << 20;
    _Float16* q1sw   = (_Float16*)(ws + 0 * MB);    // 4 MB
    _Float16* k2sw   = (_Float16*)(ws + 4 * MB);    // 4 MB
    unsigned char* vsw8 = (unsigned char*)(ws + 8 * MB);   // 4 MB (fp8 Vcat per batch)
    _Float16* wsw    = (_Float16*)(ws + 28 * MB);   // ~0.74 MB
    float*    rowsum = (float*)   (ws + 29 * MB);   // 64 KB
    _Float16* res    = (_Float16*)(ws + 30 * MB);   // 8 MB
    _Float16* xn     = (_Float16*)(ws + 46 * MB);   // 8 MB
    unsigned char* pmat8 = (unsigned char*)(ws + 78 * MB); // 64 MB (fp8 P per batch)

    prep_kernel<<<dim3(512, 10), 256, 0, stream>>>(Wq, Wv1, Wk, Wv2, Wp1, Wp2, Wf1, Wf2, Wo,
                                                   wsw, rowsum);
    proj_kernel<<<dim3(M_ / 64, 2), 256, 0, stream>>>(x1, x2, wsw,
                                                      ln1_g, ln1_b, ln2_g, ln2_b,
                                                      bq, bv1, bk, bv2,
                                                      q1sw, k2sw, vsw8);
    score_kernel<<<dim3(32, 32, 4), 256, 0, stream>>>(q1sw, k2sw, pmat8, rowsum);
    pv_kernel<<<dim3(M_ / 32), 512, 0, stream>>>(pmat8, vsw8, rowsum, wsw,
                                                 bp1, bp2, x1, x2, lnf_g, lnf_b,
                                                 res, xn);
    ffn_kernel<<<dim3(M_ / 32), 512, 0, stream>>>(xn, wsw, bf1, bf2, res,
                                                  ln3_g, ln3_b, bo, out);
}